// Round 5
// baseline (64.196 us; speedup 1.0000x reference)
//
#include <hip/hip_runtime.h>
#include <math.h>

#define N_TASKS 4096
#define N_PROC  64
#define N_EDGES 65536

#define W_PROC  1.0f
#define W_START 1.0f
#define W_END   1.0f
#define W_MAKE  1.0f
#define P_PREC  10.0f
#define P_OVER  10.0f
#define P_DUR   5.0f

#define BLOCKS     256        // all co-resident: 256 CUs, 4 waves/block, ~4KB LDS
#define OV_BLOCKS  64         // blocks 0..63 also own one processor bucket each
#define BUCKET_CAP 512        // max tasks per processor (mean 64 — huge margin)

// ws layout:
//   float [0 .. 1280)    : scalar partials, BLOCKS * 5  (nll, start, end, dur, edge)
//   float [1280 .. 1408) : ov partials, OV_BLOCKS * 2   (overlap sum, pair count)
//   byte 8192 / 8256     : cntA (proc ready) / cntB (scalar partials ready) / cntC (ov done)
//   byte 16384           : proc[] (int, N_TASKS)
// cnt* zeroed each call by a 192B hipMemsetAsync (graph-capturable).

__device__ inline void spin_ge(int* p, int target) {
    while (__hip_atomic_load(p, __ATOMIC_ACQUIRE, __HIP_MEMORY_SCOPE_AGENT) < target)
        __builtin_amdgcn_s_sleep(4);
}

__global__ __launch_bounds__(256) void fused_kernel(
        const float* __restrict__ processor,
        const float* __restrict__ start_time,
        const float* __restrict__ end_time,
        const float* __restrict__ duration,
        const float* __restrict__ y_start,
        const float* __restrict__ y_end,
        const int*   __restrict__ y_processor,
        const int*   __restrict__ edge_index,
        const float* __restrict__ makespan,
        const float* __restrict__ y_makespan,
        float* __restrict__ ws,
        int*   __restrict__ cnt,     // [0]=A, [16]=B, [32]=C (64B apart)
        int*   __restrict__ proc,
        float* __restrict__ out) {

    __shared__ float s_sh[BUCKET_CAP];
    __shared__ float e_sh[BUCKET_CAP];
    __shared__ float lds[4];
    __shared__ int   n_sh;
    __shared__ int   last_sh;

    const int tid  = threadIdx.x;
    const int lane = tid & 63;
    const int wid  = tid >> 6;
    const int wave_global = blockIdx.x * 4 + wid;   // 0..1023

    // ---- Phase A: wave-per-row log-softmax NLL + argmax (4 rows/wave) ----
    float a_nll = 0.0f;
    #pragma unroll
    for (int r = 0; r < N_TASKS / 1024; ++r) {
        const int row = wave_global * 4 + r;
        float val = processor[row * N_PROC + lane];

        float m = val;
        #pragma unroll
        for (int off = 32; off > 0; off >>= 1)
            m = fmaxf(m, __shfl_xor(m, off));

        unsigned long long eqmask = __ballot(val == m);
        int amax = __ffsll(eqmask) - 1;

        float sum = expf(val - m);
        #pragma unroll
        for (int off = 32; off > 0; off >>= 1)
            sum += __shfl_xor(sum, off);

        int y = y_processor[row];
        float vy = __shfl(val, y);

        if (lane == 0) {
            proc[row] = amax;
            a_nll += -(vy - m - logf(sum));
        }
    }

    // release proc[] early: overlap blocks can start as soon as cntA == BLOCKS
    __threadfence();
    __syncthreads();
    if (tid == 0) atomicAdd(&cnt[0], 1);

    // ---- Phase B: thread-per-row L1 terms ----
    float a_s = 0.0f, a_e = 0.0f, a_d = 0.0f;
    {
        const int row = blockIdx.x * 256 + tid;
        if (row < N_TASKS) {
            float s = start_time[row];
            float e = end_time[row];
            float d = duration[row];
            a_s = fabsf(s - y_start[row]);
            a_e = fabsf(e - y_end[row]);
            a_d = fabsf(e - s - d);
        }
    }

    // ---- Phase C: exactly one edge per thread ----
    float a_edge;
    {
        const int idx = blockIdx.x * 256 + tid;
        int snd = edge_index[idx];
        int rcv = edge_index[N_EDGES + idx];
        a_edge = fmaxf(end_time[snd] - start_time[rcv], 0.0f);
    }

    // block-reduce 5 values -> per-block partials
    float vals[5] = { a_nll, a_s, a_e, a_d, a_edge };
    #pragma unroll
    for (int k = 0; k < 5; ++k) {
        float v = vals[k];
        #pragma unroll
        for (int off = 32; off > 0; off >>= 1)
            v += __shfl_xor(v, off);
        if (lane == 0) lds[wid] = v;
        __syncthreads();
        if (tid == 0) ws[blockIdx.x * 5 + k] = lds[0] + lds[1] + lds[2] + lds[3];
        __syncthreads();
    }

    __threadfence();
    __syncthreads();
    if (tid == 0) atomicAdd(&cnt[16], 1);

    if (blockIdx.x >= OV_BLOCKS) return;

    // ---- overlap: bucket for processor p = blockIdx.x ----
    if (tid == 0) { n_sh = 0; spin_ge(&cnt[0], BLOCKS); }
    __syncthreads();
    __threadfence();

    const int p = blockIdx.x;
    for (int j = tid; j < N_TASKS; j += 256) {
        if (proc[j] == p) {
            int pos = atomicAdd(&n_sh, 1);
            if (pos < BUCKET_CAP) {
                s_sh[pos] = start_time[j];
                e_sh[pos] = end_time[j];
            }
        }
    }
    __syncthreads();

    const int n = (n_sh < BUCKET_CAP) ? n_sh : BUCKET_CAP;

    float oacc = 0.0f;
    for (int i = tid; i < n; i += 256) {
        const float si = s_sh[i];
        const float ei = e_sh[i];
        for (int j = i + 1; j < n; ++j)
            oacc += fmaxf(fminf(ei, e_sh[j]) - fmaxf(si, s_sh[j]), 0.0f);
    }

    #pragma unroll
    for (int off = 32; off > 0; off >>= 1)
        oacc += __shfl_xor(oacc, off);
    if (lane == 0) lds[wid] = oacc;
    __syncthreads();
    if (tid == 0) {
        ws[1280 + p * 2 + 0] = lds[0] + lds[1] + lds[2] + lds[3];
        ws[1280 + p * 2 + 1] = (float)(n * (n - 1) / 2);
        __threadfence();
        int old = atomicAdd(&cnt[32], 1);
        last_sh = (old == OV_BLOCKS - 1);
    }
    __syncthreads();

    if (!last_sh) return;

    // ---- finalize (last overlap block) ----
    if (tid == 0) spin_ge(&cnt[16], BLOCKS);
    __syncthreads();
    __threadfence();

    if (wid == 0) {
        float t_nll = 0.0f, t_s = 0.0f, t_e = 0.0f, t_d = 0.0f, t_edge = 0.0f;
        #pragma unroll
        for (int k = 0; k < BLOCKS / 64; ++k) {
            const float* q = ws + (lane + 64 * k) * 5;
            t_nll  += q[0];
            t_s    += q[1];
            t_e    += q[2];
            t_d    += q[3];
            t_edge += q[4];
        }
        float t_ov  = ws[1280 + lane * 2 + 0];
        float t_cnt = ws[1280 + lane * 2 + 1];

        #pragma unroll
        for (int off = 32; off > 0; off >>= 1) {
            t_nll  += __shfl_xor(t_nll, off);
            t_s    += __shfl_xor(t_s, off);
            t_e    += __shfl_xor(t_e, off);
            t_d    += __shfl_xor(t_d, off);
            t_edge += __shfl_xor(t_edge, off);
            t_ov   += __shfl_xor(t_ov, off);
            t_cnt  += __shfl_xor(t_cnt, off);
        }

        if (lane == 0) {
            float processor_loss = t_nll  / (float)N_TASKS;
            float start_loss     = t_s    / (float)N_TASKS;
            float end_loss       = t_e    / (float)N_TASKS;
            float dur_inc        = t_d    / (float)N_TASKS;
            float precedence     = t_edge / (float)N_EDGES;
            float overlap        = t_ov   / fmaxf(t_cnt, 1.0f);
            float makespan_loss  = fabsf(makespan[0] - y_makespan[0]);

            out[0] = W_PROC * processor_loss
                   + W_START * start_loss
                   + W_END * end_loss
                   + W_MAKE * makespan_loss
                   + P_PREC * precedence
                   + P_OVER * overlap
                   + P_DUR * dur_inc;
        }
    }
}

extern "C" void kernel_launch(void* const* d_in, const int* in_sizes, int n_in,
                              void* d_out, int out_size, void* d_ws, size_t ws_size,
                              hipStream_t stream) {
    const float* processor  = (const float*)d_in[0];
    const float* start_time = (const float*)d_in[1];
    const float* end_time   = (const float*)d_in[2];
    const float* duration   = (const float*)d_in[3];
    const float* makespan   = (const float*)d_in[4];
    const float* y_start    = (const float*)d_in[5];
    const float* y_end      = (const float*)d_in[6];
    const float* y_makespan = (const float*)d_in[7];
    const int*   edge_index = (const int*)d_in[8];
    const int*   y_processor= (const int*)d_in[9];

    float* ws   = (float*)d_ws;
    int*   cnt  = (int*)((char*)d_ws + 8192);
    int*   proc = (int*)((char*)d_ws + 16384);
    float* out  = (float*)d_out;

    // zero the 3 barrier counters (192B, graph-capturable memset node)
    hipMemsetAsync(cnt, 0, 192, stream);

    fused_kernel<<<BLOCKS, 256, 0, stream>>>(
        processor, start_time, end_time, duration,
        y_start, y_end, y_processor, edge_index,
        makespan, y_makespan, ws, cnt, proc, out);
}

// Round 6
// 20.678 us; speedup vs baseline: 3.1046x; 3.1046x over previous
//
#include <hip/hip_runtime.h>
#include <math.h>

#define N_TASKS 4096
#define N_PROC  64
#define N_EDGES 65536

#define W_PROC  1.0f
#define W_START 1.0f
#define W_END   1.0f
#define W_MAKE  1.0f
#define P_PREC  10.0f
#define P_OVER  10.0f
#define P_DUR   5.0f

#define PT_BLOCKS 256         // 1024 waves -> all 256 CUs busy
#define OV_BLOCKS 64          // one block per processor
#define OV_THREADS 512
#define BUCKET_CAP 512        // max tasks per processor (mean 64 — huge margin)

// ws float layout:
// [0 .. 1280)      pt partials: PT_BLOCKS * 5  (nll, start, end, dur, edge)
// [1280 .. 1408)   ov partials: OV_BLOCKS * 2  (overlap sum, pair count)
// [1408]           done counter (int)
// proc[] (int, N_TASKS) at byte offset 16384 (16B aligned for int4 loads).

// ---------- kernel 1: per-task softmax/NLL/argmax + L1 terms + edge term ----------
// 256 blocks x 256 threads; each wave owns 4 rows; each thread owns 1 edge.
__global__ __launch_bounds__(256) void per_task_edge_kernel(
        const float* __restrict__ processor,
        const float* __restrict__ start_time,
        const float* __restrict__ end_time,
        const float* __restrict__ duration,
        const float* __restrict__ y_start,
        const float* __restrict__ y_end,
        const int*   __restrict__ y_processor,
        const int*   __restrict__ edge_index,
        float* __restrict__ ws,
        int*   __restrict__ proc_out) {
    const int tid  = threadIdx.x;
    const int lane = tid & 63;
    const int wid  = tid >> 6;
    const int wave_global = blockIdx.x * 4 + wid;   // 0..1023

    // reset the done counter for kernel 2 (fresh every call -> deterministic)
    if (blockIdx.x == 0 && tid == 0) ((int*)ws)[1408] = 0;

    float a_nll = 0.0f;

    // Phase A: wave-per-row log-softmax NLL + argmax (4 rows per wave,
    // independent chains -> compiler software-pipelines them)
    #pragma unroll
    for (int r = 0; r < N_TASKS / 1024; ++r) {
        const int row = wave_global * 4 + r;
        float val = processor[row * N_PROC + lane];

        float m = val;
        #pragma unroll
        for (int off = 32; off > 0; off >>= 1)
            m = fmaxf(m, __shfl_xor(m, off));

        unsigned long long eqmask = __ballot(val == m);
        int amax = __ffsll(eqmask) - 1;

        float sum = expf(val - m);
        #pragma unroll
        for (int off = 32; off > 0; off >>= 1)
            sum += __shfl_xor(sum, off);

        int y = y_processor[row];
        float vy = __shfl(val, y);

        if (lane == 0) {
            proc_out[row] = amax;
            a_nll += -(vy - m - logf(sum));
        }
    }

    // Phase B: thread-per-row L1 terms (blocks 0..15 cover all 4096 rows)
    float a_s = 0.0f, a_e = 0.0f, a_d = 0.0f;
    {
        const int row = blockIdx.x * 256 + tid;
        if (row < N_TASKS) {
            float s = start_time[row];
            float e = end_time[row];
            float d = duration[row];
            a_s = fabsf(s - y_start[row]);
            a_e = fabsf(e - y_end[row]);
            a_d = fabsf(e - s - d);
        }
    }

    // Phase C: exactly one edge per thread (65536 threads)
    float a_edge;
    {
        const int idx = blockIdx.x * 256 + tid;
        int snd = edge_index[idx];
        int rcv = edge_index[N_EDGES + idx];
        a_edge = fmaxf(end_time[snd] - start_time[rcv], 0.0f);
    }

    // Single-barrier reduction tail: 5 independent wave-reduces (ILP),
    // one LDS write per wave, one sync, 5 threads store the partials.
    __shared__ float lds[4 * 5];
    float vals[5] = { a_nll, a_s, a_e, a_d, a_edge };
    #pragma unroll
    for (int k = 0; k < 5; ++k) {
        float v = vals[k];
        #pragma unroll
        for (int off = 32; off > 0; off >>= 1)
            v += __shfl_xor(v, off);
        vals[k] = v;
    }
    if (lane == 0) {
        #pragma unroll
        for (int k = 0; k < 5; ++k) lds[wid * 5 + k] = vals[k];
    }
    __syncthreads();
    if (tid < 5) {
        ws[blockIdx.x * 5 + tid] = lds[tid] + lds[5 + tid] + lds[10 + tid] + lds[15 + tid];
    }
}

// ---------- kernel 2: bucketed overlap + finalize (last-block pattern) ----------
// 64 blocks x 512 threads; block p gathers tasks with proc==p (int4 scan),
// computes within-bucket pairs, last block reduces everything.
__global__ __launch_bounds__(OV_THREADS) void overlap_finalize_kernel(
        const float* __restrict__ s,
        const float* __restrict__ e,
        const int*   __restrict__ proc,
        const float* __restrict__ makespan,
        const float* __restrict__ y_makespan,
        float* __restrict__ ws,
        float* __restrict__ out) {
    __shared__ float s_sh[BUCKET_CAP];
    __shared__ float e_sh[BUCKET_CAP];
    __shared__ int   n_sh;
    __shared__ float lds[OV_THREADS / 64];
    __shared__ int   last_sh;

    const int tid  = threadIdx.x;
    const int lane = tid & 63;
    const int wid  = tid >> 6;           // 0..7
    const int p    = blockIdx.x;

    if (tid == 0) n_sh = 0;
    __syncthreads();

    // vectorized gather scan: 4096 ints as 1024 int4, 2 iters per thread
    const int4* proc4 = (const int4*)proc;
    #pragma unroll
    for (int it = 0; it < (N_TASKS / 4) / OV_THREADS; ++it) {
        const int j4 = tid + it * OV_THREADS;
        int4 v = proc4[j4];
        const int base = j4 * 4;
        if (v.x == p) { int pos = atomicAdd(&n_sh, 1); if (pos < BUCKET_CAP) { s_sh[pos] = s[base+0]; e_sh[pos] = e[base+0]; } }
        if (v.y == p) { int pos = atomicAdd(&n_sh, 1); if (pos < BUCKET_CAP) { s_sh[pos] = s[base+1]; e_sh[pos] = e[base+1]; } }
        if (v.z == p) { int pos = atomicAdd(&n_sh, 1); if (pos < BUCKET_CAP) { s_sh[pos] = s[base+2]; e_sh[pos] = e[base+2]; } }
        if (v.w == p) { int pos = atomicAdd(&n_sh, 1); if (pos < BUCKET_CAP) { s_sh[pos] = s[base+3]; e_sh[pos] = e[base+3]; } }
    }
    __syncthreads();

    const int n = (n_sh < BUCKET_CAP) ? n_sh : BUCKET_CAP;

    // all within-bucket unordered pairs (symmetric term)
    float oacc = 0.0f;
    for (int i = tid; i < n; i += OV_THREADS) {
        const float si = s_sh[i];
        const float ei = e_sh[i];
        for (int j = i + 1; j < n; ++j)
            oacc += fmaxf(fminf(ei, e_sh[j]) - fmaxf(si, s_sh[j]), 0.0f);
    }

    #pragma unroll
    for (int off = 32; off > 0; off >>= 1)
        oacc += __shfl_xor(oacc, off);
    if (lane == 0) lds[wid] = oacc;
    __syncthreads();
    if (tid == 0) {
        float t = 0.0f;
        #pragma unroll
        for (int w = 0; w < OV_THREADS / 64; ++w) t += lds[w];
        ws[1280 + p * 2 + 0] = t;
        ws[1280 + p * 2 + 1] = (float)(n * (n - 1) / 2);
        __threadfence();
        int old = atomicAdd(&((int*)ws)[1408], 1);
        last_sh = (old == OV_BLOCKS - 1);
    }
    __syncthreads();

    if (!last_sh) return;
    __threadfence();

    // final reduction by wave 0 of the last block
    if (wid == 0) {
        float t_nll = 0.0f, t_s = 0.0f, t_e = 0.0f, t_d = 0.0f, t_edge = 0.0f;
        #pragma unroll
        for (int k = 0; k < PT_BLOCKS / 64; ++k) {
            const float* q = ws + (lane + 64 * k) * 5;
            t_nll  += q[0];
            t_s    += q[1];
            t_e    += q[2];
            t_d    += q[3];
            t_edge += q[4];
        }
        float t_ov  = ws[1280 + lane * 2 + 0];
        float t_cnt = ws[1280 + lane * 2 + 1];

        #pragma unroll
        for (int off = 32; off > 0; off >>= 1) {
            t_nll  += __shfl_xor(t_nll, off);
            t_s    += __shfl_xor(t_s, off);
            t_e    += __shfl_xor(t_e, off);
            t_d    += __shfl_xor(t_d, off);
            t_edge += __shfl_xor(t_edge, off);
            t_ov   += __shfl_xor(t_ov, off);
            t_cnt  += __shfl_xor(t_cnt, off);
        }

        if (lane == 0) {
            float processor_loss = t_nll  / (float)N_TASKS;
            float start_loss     = t_s    / (float)N_TASKS;
            float end_loss       = t_e    / (float)N_TASKS;
            float dur_inc        = t_d    / (float)N_TASKS;
            float precedence     = t_edge / (float)N_EDGES;
            float overlap        = t_ov   / fmaxf(t_cnt, 1.0f);
            float makespan_loss  = fabsf(makespan[0] - y_makespan[0]);

            out[0] = W_PROC * processor_loss
                   + W_START * start_loss
                   + W_END * end_loss
                   + W_MAKE * makespan_loss
                   + P_PREC * precedence
                   + P_OVER * overlap
                   + P_DUR * dur_inc;
        }
    }
}

extern "C" void kernel_launch(void* const* d_in, const int* in_sizes, int n_in,
                              void* d_out, int out_size, void* d_ws, size_t ws_size,
                              hipStream_t stream) {
    const float* processor  = (const float*)d_in[0];
    const float* start_time = (const float*)d_in[1];
    const float* end_time   = (const float*)d_in[2];
    const float* duration   = (const float*)d_in[3];
    const float* makespan   = (const float*)d_in[4];
    const float* y_start    = (const float*)d_in[5];
    const float* y_end      = (const float*)d_in[6];
    const float* y_makespan = (const float*)d_in[7];
    const int*   edge_index = (const int*)d_in[8];
    const int*   y_processor= (const int*)d_in[9];

    float* ws   = (float*)d_ws;
    int*   proc = (int*)((char*)d_ws + 16384);
    float* out  = (float*)d_out;

    per_task_edge_kernel<<<PT_BLOCKS, 256, 0, stream>>>(
        processor, start_time, end_time, duration,
        y_start, y_end, y_processor, edge_index, ws, proc);

    overlap_finalize_kernel<<<OV_BLOCKS, OV_THREADS, 0, stream>>>(
        start_time, end_time, proc, makespan, y_makespan, ws, out);
}